// Round 1
// baseline (215.064 us; speedup 1.0000x reference)
//
#include <hip/hip_runtime.h>

// Problem constants (B, T, D, U from the reference; U unused — see below).
#define BB 32
#define TT 1024
#define DD 1024
#define TCHUNKS 32
#define TSUB (TT / TCHUNKS)  // 32 timesteps per chunk

// Key insight: the reference's softmax is over a SINGLETON axis, so
// attention_weights == 1.0 exactly, coverage[b,t] == t exactly, and
// context_vector == sum_t values[b,t,:]. All GEMM/tanh/scan work is dead.

// Phase 1: partial column sums. Grid (TCHUNKS, BB), 256 threads.
// Each thread owns one float4 column (d4 = threadIdx.x) of one (b, t-chunk).
// Per iteration a wave reads 64 lanes x 16 B = 1 KB contiguous — fully coalesced.
__global__ __launch_bounds__(256) void sum_partial_kernel(
    const float* __restrict__ values, float* __restrict__ partial) {
  const int chunk = blockIdx.x;
  const int b = blockIdx.y;
  const int d4 = threadIdx.x;  // 0..255 -> d = 4*d4
  const float4* vp = reinterpret_cast<const float4*>(values) +
                     ((size_t)b * TT + (size_t)chunk * TSUB) * (DD / 4) + d4;
  float4 acc = make_float4(0.f, 0.f, 0.f, 0.f);
#pragma unroll
  for (int t = 0; t < TSUB; ++t) {
    float4 v = vp[(size_t)t * (DD / 4)];
    acc.x += v.x;
    acc.y += v.y;
    acc.z += v.z;
    acc.w += v.w;
  }
  float4* pp = reinterpret_cast<float4*>(partial) +
               ((size_t)chunk * BB + b) * (DD / 4) + d4;
  *pp = acc;
}

// Phase 2: reduce TCHUNKS partials -> context_vector [BB, DD].
__global__ __launch_bounds__(256) void final_reduce_kernel(
    const float* __restrict__ partial, float* __restrict__ ctx) {
  const int idx = blockIdx.x * 256 + threadIdx.x;  // over BB*DD/4 = 8192 float4
  const float4* pp = reinterpret_cast<const float4*>(partial);
  float4 acc = make_float4(0.f, 0.f, 0.f, 0.f);
#pragma unroll
  for (int c = 0; c < TCHUNKS; ++c) {
    float4 v = pp[(size_t)c * (BB * DD / 4) + idx];
    acc.x += v.x;
    acc.y += v.y;
    acc.z += v.z;
    acc.w += v.w;
  }
  reinterpret_cast<float4*>(ctx)[idx] = acc;
}

// Atomic fallback for tiny ws_size: accumulate straight into ctx.
__global__ __launch_bounds__(256) void sum_atomic_kernel(
    const float* __restrict__ values, float* __restrict__ ctx) {
  const int chunk = blockIdx.x;
  const int b = blockIdx.y;
  const int d4 = threadIdx.x;
  const float4* vp = reinterpret_cast<const float4*>(values) +
                     ((size_t)b * TT + (size_t)chunk * TSUB) * (DD / 4) + d4;
  float4 acc = make_float4(0.f, 0.f, 0.f, 0.f);
#pragma unroll
  for (int t = 0; t < TSUB; ++t) {
    float4 v = vp[(size_t)t * (DD / 4)];
    acc.x += v.x;
    acc.y += v.y;
    acc.z += v.z;
    acc.w += v.w;
  }
  float* o = ctx + (size_t)b * DD + (size_t)d4 * 4;
  atomicAdd(o + 0, acc.x);
  atomicAdd(o + 1, acc.y);
  atomicAdd(o + 2, acc.z);
  atomicAdd(o + 3, acc.w);
}

// attention_weights = 1.0 everywhere; coverage[b,t] = t.
__global__ __launch_bounds__(256) void fill_kernel(float* __restrict__ aw,
                                                   float* __restrict__ cov) {
  const int idx = blockIdx.x * 256 + threadIdx.x;  // BB*TT = 32768
  aw[idx] = 1.0f;
  cov[idx] = (float)(idx & (TT - 1));  // t = idx % TT (TT is pow2)
}

extern "C" void kernel_launch(void* const* d_in, const int* in_sizes, int n_in,
                              void* d_out, int out_size, void* d_ws,
                              size_t ws_size, hipStream_t stream) {
  // Inputs (setup_inputs order): 0=query, 1=values, 2=W1, 3=b1, 4=W2, 5=b2,
  // 6=W3, 7=b3, 8=V, 9=bV. Only `values` matters.
  const float* values = (const float*)d_in[1];

  // Output layout (tuple concatenated flat, f32):
  //   context_vector [BB*DD] | attention_weights [BB*TT] | coverage [BB*TT]
  float* out = (float*)d_out;
  float* ctx = out;
  float* aw = out + (size_t)BB * DD;
  float* cov = aw + (size_t)BB * TT;

  fill_kernel<<<(BB * TT) / 256, 256, 0, stream>>>(aw, cov);

  const size_t need = (size_t)TCHUNKS * BB * DD * sizeof(float);
  if (ws_size >= need) {
    float* partial = (float*)d_ws;
    dim3 g1(TCHUNKS, BB);
    sum_partial_kernel<<<g1, 256, 0, stream>>>(values, partial);
    final_reduce_kernel<<<(BB * DD / 4) / 256, 256, 0, stream>>>(partial, ctx);
  } else {
    hipMemsetAsync(ctx, 0, (size_t)BB * DD * sizeof(float), stream);
    dim3 g1(TCHUNKS, BB);
    sum_atomic_kernel<<<g1, 256, 0, stream>>>(values, ctx);
  }
}